// Round 16
// baseline (991.411 us; speedup 1.0000x reference)
//
#include <hip/hip_runtime.h>

#define N_NODES 20000
#define N_EDGES 320000
#define HID 128
#define NG 64
#define TGT 32
#define DEPTHL 4

typedef __attribute__((ext_vector_type(8))) short s16x8;
typedef __attribute__((ext_vector_type(4))) short s16x4;
typedef __attribute__((ext_vector_type(4))) float f32x4;

__device__ __forceinline__ unsigned short f2b(float f) {
  unsigned u = __builtin_bit_cast(unsigned, f);
  u = (u + 0x7FFFu + ((u >> 16) & 1u)) >> 16;
  return (unsigned short)u;
}
__device__ __forceinline__ float b2f(unsigned short s) {
  return __builtin_bit_cast(float, ((unsigned)s) << 16);
}
__device__ __forceinline__ float silu_f(float x) { return x / (1.f + __expf(-x)); }

__device__ __forceinline__ unsigned fkey(float f) {
  unsigned u = __builtin_bit_cast(unsigned, f);
  return (u & 0x80000000u) ? ~u : (u | 0x80000000u);
}
__device__ __forceinline__ float unkey(unsigned k) {
  unsigned u = (k & 0x80000000u) ? (k ^ 0x80000000u) : ~k;
  return __builtin_bit_cast(float, u);
}

__device__ __forceinline__ f32x4 mfma16(s16x8 a, s16x8 b, f32x4 c) {
  return __builtin_amdgcn_mfma_f32_16x16x32_bf16(a, b, c, 0, 0, 0);
}

// wave-internal LDS write->read fence (guide rule 18)
__device__ __forceinline__ void lds_fence() {
  asm volatile("s_waitcnt lgkmcnt(0)" ::: "memory");
  __builtin_amdgcn_sched_barrier(0);
}

__device__ __forceinline__ s16x8 pack8(float4 a, float4 b) {
  s16x8 p;
  p[0]=(short)f2b(a.x); p[1]=(short)f2b(a.y); p[2]=(short)f2b(a.z); p[3]=(short)f2b(a.w);
  p[4]=(short)f2b(b.x); p[5]=(short)f2b(b.y); p[6]=(short)f2b(b.z); p[7]=(short)f2b(b.w);
  return p;
}

// ---------------- weight packing into MFMA fragment layout (bf16) -------------
// msg weights: per-layer contiguous blob [W1 frags (49152) | W2 frags (16384)],
// 16x16x32 fragment layout for all matrices.
__global__ void pack_weights(const float* __restrict__ mW1, const float* __restrict__ mW2,
                             const float* __restrict__ uW1, const float* __restrict__ uW2,
                             const float* __restrict__ nW1, const float* __restrict__ nW2,
                             short* __restrict__ pMsg,
                             short* __restrict__ puW1, short* __restrict__ puW2,
                             short* __restrict__ pnW1, short* __restrict__ pnW2) {
  int i = blockIdx.x * 256 + threadIdx.x;
  const float* src; short* dst; int K, r;
  if (i < 196608)      { int l = i/49152; r = i % 49152; src = mW1 + l*49152; dst = pMsg + l*65536 + r;        K = 384; }
  else if (i < 262144) { int q = i - 196608; int l = q/16384; r = q % 16384; src = mW2 + l*16384; dst = pMsg + l*65536 + 49152 + r; K = 128; }
  else if (i < 327680) { int q = i - 262144; src = uW1 + (q/16384)*16384; dst = puW1 + q; r = q % 16384; K = 128; }
  else if (i < 393216) { int q = i - 327680; src = uW2 + (q/16384)*16384; dst = puW2 + q; r = q % 16384; K = 128; }
  else if (i < 409600) { int q = i - 393216; src = nW1; dst = pnW1 + q; r = q; K = 128; }
  else if (i < 425984) { int q = i - 409600; src = nW2; dst = pnW2 + q; r = q; K = 128; }
  else return;
  int j = r & 7, lane = (r >> 3) & 63, q2 = r >> 9;
  int KT = K >> 5;
  int kt = q2 % KT, ct = q2 / KT;
  int k = kt*32 + ((lane >> 4) << 3) + j;
  int col = ct*16 + (lane & 15);
  dst[0] = (short)f2b(src[k*HID + col]);
}

// ---------------- edge sort by dst: hist -> scan -> scatter -------------------
__global__ void sort_init(int* __restrict__ hist, int* __restrict__ cursor) {
  int i = blockIdx.x * 256 + threadIdx.x;
  if (i < N_NODES) { hist[i] = 0; cursor[i] = 0; }
}

__global__ void hist_kernel(const int* __restrict__ dst, int* __restrict__ hist) {
  int e = blockIdx.x * 256 + threadIdx.x;
  if (e < N_EDGES) atomicAdd(&hist[dst[e]], 1);
}

__global__ __launch_bounds__(1024) void scan_kernel(const int* __restrict__ hist,
                                                    int* __restrict__ offs) {
  __shared__ int part[1024];
  int t = threadIdx.x;
  int base = t * 20;
  int loc[20];
  int s = 0;
#pragma unroll
  for (int i = 0; i < 20; ++i) {
    loc[i] = s;
    int n = base + i;
    s += (n < N_NODES ? hist[n] : 0);
  }
  part[t] = s;
  __syncthreads();
  for (int st = 1; st < 1024; st <<= 1) {
    int v = (t >= st) ? part[t - st] : 0;
    __syncthreads();
    part[t] += v;
    __syncthreads();
  }
  int pre = (t > 0) ? part[t - 1] : 0;
#pragma unroll
  for (int i = 0; i < 20; ++i) {
    int n = base + i;
    if (n < N_NODES) offs[n] = pre + loc[i];
  }
}

__global__ void scatter_kernel(const int* __restrict__ src, const int* __restrict__ dst,
                               const float* __restrict__ ea, const int* __restrict__ offs,
                               int* __restrict__ cursor,
                               unsigned short* __restrict__ ssrc,
                               unsigned short* __restrict__ sdst,
                               float* __restrict__ sea) {
  int e = blockIdx.x * 256 + threadIdx.x;
  if (e >= N_EDGES) return;
  int d = dst[e];
  int pos = offs[d] + atomicAdd(&cursor[d], 1);
  ssrc[pos] = (unsigned short)src[e];
  sdst[pos] = (unsigned short)d;
  sea[pos] = ea[e];
}

// ---------------- edge feature init (sorted order) ----------------------------
__global__ void edge_init(const float* __restrict__ sea, const float* __restrict__ eW,
                          const float* __restrict__ eb, unsigned short* __restrict__ e) {
  __shared__ float feat[2][9];
  int t = threadIdx.x;
  int le = t >> 7, c = t & 127;
  int edge = blockIdx.x * 2 + le;
  if (c < 9) {
    float d = sea[edge];
    float sc = (float)(1 << (c & 3));
    float v;
    if (c < 4) v = sinf(d / sc);
    else if (c < 8) v = cosf(d / sc);
    else v = d;
    feat[le][c] = v;
  }
  __syncthreads();
  float acc = eb[c];
#pragma unroll
  for (int j = 0; j < 9; ++j) acc += feat[le][j] * eW[j*HID + c];
  acc = silu_f(silu_f(acc));
  e[edge*HID + c] = f2b(acc);
}

// h init (f32 + bf16 mirror) AND agg zero-init
__global__ void init_h(float* __restrict__ h, const float* __restrict__ ne,
                       float* __restrict__ agg, unsigned short* __restrict__ hb) {
  int i = blockIdx.x * 256 + threadIdx.x;
  if (i < N_NODES * HID) {
    float v = ne[i & 127];
    h[i] = v; hb[i] = f2b(v); agg[i] = 0.f;
  }
}

__global__ void init_read(float* __restrict__ s, float* __restrict__ cnt, unsigned* __restrict__ mx) {
  int i = blockIdx.x * 256 + threadIdx.x;
  if (i < NG * HID) { s[i] = 0.f; mx[i] = 0x007FFFFFu; } // key(-inf)
  if (i < NG) cnt[i] = 0.f;
}

// ---------------- fused per-layer edge kernel ---------------------------------
// 8 independent waves/block (512 threads), 16 edges/wave, no block barriers.
// Per-wave code identical to round-14; bigger blocks raise resident waves/CU
// past the ~3-block scheduler granularity (target: VGPR-capped 50%).
__global__ __launch_bounds__(512) void msg_kernel(
    const unsigned short* __restrict__ hb, unsigned short* __restrict__ e,
    const unsigned short* __restrict__ ssrc, const unsigned short* __restrict__ sdst,
    const short* __restrict__ Wp, const float* __restrict__ b1,
    const float* __restrict__ b2,
    const float* __restrict__ sW, const float* __restrict__ sbp,
    float* __restrict__ agg) {
  __shared__ __align__(16) short t1f[8][2048];   // [k8=16][edge=16][8] per wave
  const short* W1p = Wp;
  const short* W2p = Wp + 49152;
  int t = threadIdx.x;
  int wv = t >> 6, lane = t & 63;
  int l15 = lane & 15, hi = lane >> 4;
  int edge = blockIdx.x * 128 + wv * 16 + l15;
  int si = ssrc[edge];
  int d  = sdst[edge];

  // ---- B-fragments: all 12 issued up-front (one exposed gather latency) ----
  s16x8 bfrag[12];
#pragma unroll
  for (int kt = 0; kt < 4; ++kt)
    bfrag[kt] = *(const s16x8*)(hb + si*HID + kt*32 + hi*8);
#pragma unroll
  for (int kt = 0; kt < 4; ++kt)
    bfrag[4+kt] = *(const s16x8*)(hb + d*HID + kt*32 + hi*8);
#pragma unroll
  for (int kt = 0; kt < 4; ++kt)
    bfrag[8+kt] = *(const s16x8*)(e + (size_t)edge*HID + kt*32 + hi*8);

  // ---- GEMM1: t1^T = W1^T @ m_in^T (K=384) ----
  f32x4 acc1[8];
#pragma unroll
  for (int ct = 0; ct < 8; ++ct) acc1[ct] = f32x4{0.f, 0.f, 0.f, 0.f};
#pragma unroll
  for (int kt = 0; kt < 12; ++kt) {
#pragma unroll
    for (int ct = 0; ct < 8; ++ct) {
      s16x8 afr = *(const s16x8*)(W1p + ((ct*12 + kt)*64 + lane)*8);
      acc1[ct] = mfma16(afr, bfrag[kt], acc1[ct]);
    }
  }
  // ---- silu + transpose via wave-private LDS ----
  short* myt1 = &t1f[wv][0];
#pragma unroll
  for (int ct = 0; ct < 8; ++ct) {
    f32x4 bias = *(const f32x4*)(b1 + ct*16 + hi*4);
    s16x4 pk4;
#pragma unroll
    for (int r = 0; r < 4; ++r) pk4[r] = (short)f2b(silu_f(acc1[ct][r] + bias[r]));
    *(s16x4*)&myt1[((2*ct + (hi >> 1))*16 + l15)*8 + (hi & 1)*4] = pk4;
  }
  lds_fence();   // order t1f write -> read within this wave

  // ---- GEMM2 ----
  f32x4 acc2[8];
#pragma unroll
  for (int ct = 0; ct < 8; ++ct) acc2[ct] = f32x4{0.f, 0.f, 0.f, 0.f};
#pragma unroll
  for (int kt = 0; kt < 4; ++kt) {
    s16x8 bfr = *(const s16x8*)&myt1[((kt*4 + hi)*16 + l15)*8];
#pragma unroll
    for (int ct = 0; ct < 8; ++ct) {
      s16x8 afr = *(const s16x8*)(W2p + ((ct*4 + kt)*64 + lane)*8);
      acc2[ct] = mfma16(afr, bfr, acc2[ct]);
    }
  }

  // ---- eold prefetch (latency hides under pass 1) ----
  uint2 eold[8];
#pragma unroll
  for (int ct = 0; ct < 8; ++ct)
    eold[ct] = *(const uint2*)(e + (size_t)edge*HID + ct*16 + hi*4);

  // ---- pass 1: m = silu(acc2+b2) packed to bf16 (mpk); gate dot ----
  uint2 mpk[8];
  float wpart = 0.f;
#pragma unroll
  for (int ct = 0; ct < 8; ++ct) {
    f32x4 bias = *(const f32x4*)(b2 + ct*16 + hi*4);
    f32x4 swv  = *(const f32x4*)(sW + ct*16 + hi*4);
    f32x4 mv;
#pragma unroll
    for (int r = 0; r < 4; ++r) {
      mv[r] = silu_f(acc2[ct][r] + bias[r]);
      wpart += mv[r] * swv[r];
    }
    mpk[ct].x = (unsigned)f2b(mv[0]) | ((unsigned)f2b(mv[1]) << 16);
    mpk[ct].y = (unsigned)f2b(mv[2]) | ((unsigned)f2b(mv[3]) << 16);
  }
  wpart += __shfl_xor(wpart, 16);
  wpart += __shfl_xor(wpart, 32);
  float wg = 1.f / (1.f + __expf(-(wpart + sbp[0])));

  // head lanes + segment masks (dst-sorted 16-edge group)
  int pd = __shfl_up(d, 1, 16);
  bool head = (l15 == 0) || (pd != d);
  int okbits = 0;
#pragma unroll
  for (int i = 0; i < 4; ++i) {
    int off = 1 << i;
    int nd = __shfl_down(d, off, 16);
    if ((l15 + off < 16) && (nd == d)) okbits |= (1 << i);
  }
  float* aggrow = agg + d*HID;

  // ---- pass 2 per ct: unpack m, e RMW, segmented suffix-sum, head atomics ----
#pragma unroll
  for (int ct = 0; ct < 8; ++ct) {
    float m0 = b2f((unsigned short)(mpk[ct].x & 0xFFFFu));
    float m1 = b2f((unsigned short)(mpk[ct].x >> 16));
    float m2 = b2f((unsigned short)(mpk[ct].y & 0xFFFFu));
    float m3 = b2f((unsigned short)(mpk[ct].y >> 16));

    uint2 cur = eold[ct];
    float f0 = b2f((unsigned short)(cur.x & 0xFFFFu)) + m0;
    float f1 = b2f((unsigned short)(cur.x >> 16))     + m1;
    float f2v = b2f((unsigned short)(cur.y & 0xFFFFu)) + m2;
    float f3 = b2f((unsigned short)(cur.y >> 16))     + m3;
    uint2 nw;
    nw.x = (unsigned)f2b(f0)  | ((unsigned)f2b(f1) << 16);
    nw.y = (unsigned)f2b(f2v) | ((unsigned)f2b(f3) << 16);
    *(uint2*)(e + (size_t)edge*HID + ct*16 + hi*4) = nw;

    f32x4 v;
    v[0] = m0 * wg; v[1] = m1 * wg; v[2] = m2 * wg; v[3] = m3 * wg;
#pragma unroll
    for (int i = 0; i < 4; ++i) {
      int off = 1 << i;
      bool ok = (okbits >> i) & 1;
#pragma unroll
      for (int r = 0; r < 4; ++r) {
        float nv = __shfl_down(v[r], off, 16);
        if (ok) v[r] += nv;
      }
    }
    if (head) {
      float* ap = aggrow + ct*16 + hi*4;
      atomicAdd(ap + 0, v[0]);
      atomicAdd(ap + 1, v[1]);
      atomicAdd(ap + 2, v[2]);
      atomicAdd(ap + 3, v[3]);
    }
  }
}

// ---------------- node MLP kernel (8 independent waves/block, 16 nodes/wave) --
// MODE 0: h += MLP(agg+h), hb = bf16(h), agg = 0.  MODE 1: out = MLP(h).
template<int MODE>
__global__ __launch_bounds__(512) void node_kernel(
    float* __restrict__ h, float* __restrict__ agg,
    const short* __restrict__ W1p, const float* __restrict__ b1,
    const short* __restrict__ W2p, const float* __restrict__ b2,
    float* __restrict__ out, unsigned short* __restrict__ hb) {
  __shared__ __align__(16) short t1f[8][2048];
  int t = threadIdx.x;
  int wv = t >> 6, lane = t & 63;
  int l15 = lane & 15, hi = lane >> 4;
  int node = blockIdx.x * 128 + wv * 16 + l15;
  bool valid = node < N_NODES;
  int nodec = valid ? node : (N_NODES - 1);

  s16x8 bfrag[4];
#pragma unroll
  for (int kt = 0; kt < 4; ++kt) {
    const float* hp = h + nodec*HID + kt*32 + hi*8;
    float4 v0 = *(const float4*)hp;
    float4 v1 = *(const float4*)(hp + 4);
    if (MODE == 0) {
      float* ap = agg + nodec*HID + kt*32 + hi*8;
      float4 a0 = *(const float4*)ap;
      float4 a1 = *(const float4*)(ap + 4);
      v0.x += a0.x; v0.y += a0.y; v0.z += a0.z; v0.w += a0.w;
      v1.x += a1.x; v1.y += a1.y; v1.z += a1.z; v1.w += a1.w;
      if (valid) {
        float4 z = {0.f, 0.f, 0.f, 0.f};
        *(float4*)ap = z;
        *(float4*)(ap + 4) = z;
      }
    }
    bfrag[kt] = pack8(v0, v1);
  }

  f32x4 acc1[8];
#pragma unroll
  for (int ct = 0; ct < 8; ++ct) acc1[ct] = f32x4{0.f, 0.f, 0.f, 0.f};
#pragma unroll
  for (int kt = 0; kt < 4; ++kt) {
#pragma unroll
    for (int ct = 0; ct < 8; ++ct) {
      s16x8 afr = *(const s16x8*)(W1p + ((ct*4 + kt)*64 + lane)*8);
      acc1[ct] = mfma16(afr, bfrag[kt], acc1[ct]);
    }
  }
  short* myt1 = &t1f[wv][0];
#pragma unroll
  for (int ct = 0; ct < 8; ++ct) {
    f32x4 bias = *(const f32x4*)(b1 + ct*16 + hi*4);
    s16x4 pk4;
#pragma unroll
    for (int r = 0; r < 4; ++r) pk4[r] = (short)f2b(silu_f(acc1[ct][r] + bias[r]));
    *(s16x4*)&myt1[((2*ct + (hi >> 1))*16 + l15)*8 + (hi & 1)*4] = pk4;
  }
  lds_fence();

  f32x4 acc2[8];
#pragma unroll
  for (int ct = 0; ct < 8; ++ct) acc2[ct] = f32x4{0.f, 0.f, 0.f, 0.f};
#pragma unroll
  for (int kt = 0; kt < 4; ++kt) {
    s16x8 bfr = *(const s16x8*)&myt1[((kt*4 + hi)*16 + l15)*8];
#pragma unroll
    for (int ct = 0; ct < 8; ++ct) {
      s16x8 afr = *(const s16x8*)(W2p + ((ct*4 + kt)*64 + lane)*8);
      acc2[ct] = mfma16(afr, bfr, acc2[ct]);
    }
  }
  if (valid) {
#pragma unroll
    for (int ct = 0; ct < 8; ++ct) {
      f32x4 bias = *(const f32x4*)(b2 + ct*16 + hi*4);
      float* op = (MODE == 0 ? h : out) + node*HID + ct*16 + hi*4;
      float4 res;
      if (MODE == 0) {
        float4 cur = *(const float4*)op;
        res.x = cur.x + acc2[ct][0] + bias[0];
        res.y = cur.y + acc2[ct][1] + bias[1];
        res.z = cur.z + acc2[ct][2] + bias[2];
        res.w = cur.w + acc2[ct][3] + bias[3];
      } else {
        res.x = acc2[ct][0] + bias[0];
        res.y = acc2[ct][1] + bias[1];
        res.z = acc2[ct][2] + bias[2];
        res.w = acc2[ct][3] + bias[3];
      }
      *(float4*)op = res;
      if (MODE == 0) {
        uint2 nb;
        nb.x = (unsigned)f2b(res.x) | ((unsigned)f2b(res.y) << 16);
        nb.y = (unsigned)f2b(res.z) | ((unsigned)f2b(res.w) << 16);
        *(uint2*)(hb + node*HID + ct*16 + hi*4) = nb;
      }
    }
  }
}

// ---------------- per-graph reductions (sorted batch, per-thread run-flush) ---
__global__ void accum_kernel(const float* __restrict__ h2, const int* __restrict__ batch,
                             float* __restrict__ s, float* __restrict__ cnt,
                             unsigned* __restrict__ mx) {
  int c = threadIdx.x & 127;
  int lr = threadIdx.x >> 7;
  int base = blockIdx.x * 64;
  int cur = -1; float sum = 0.f, mxv = -3.0e38f, count = 0.f;
  for (int i = 0; i < 32; ++i) {
    int node = base + lr + 2 * i;
    if (node >= N_NODES) break;
    int g = batch[node];
    if (g != cur) {
      if (cur >= 0) {
        atomicAdd(&s[cur*HID + c], sum);
        atomicMax(&mx[cur*HID + c], fkey(mxv));
        if (c == 0) atomicAdd(&cnt[cur], count);
      }
      cur = g; sum = 0.f; mxv = -3.0e38f; count = 0.f;
    }
    float v = h2[node*HID + c];
    sum += v; mxv = fmaxf(mxv, v); count += 1.f;
  }
  if (cur >= 0) {
    atomicAdd(&s[cur*HID + c], sum);
    atomicMax(&mx[cur*HID + c], fkey(mxv));
    if (c == 0) atomicAdd(&cnt[cur], count);
  }
}

// ---------------- readout MLP -------------------------------------------------
__global__ void final_kernel(const float* __restrict__ s, const float* __restrict__ cnt,
                             const unsigned* __restrict__ mx,
                             const float* __restrict__ W1, const float* __restrict__ b1,
                             const float* __restrict__ W2, const float* __restrict__ b2,
                             float* __restrict__ out) {
  __shared__ float ro[3 * HID];
  __shared__ float r1[HID];
  int g = blockIdx.x, c = threadIdx.x;
  float sv = s[g*HID + c];
  float cn = cnt[g];
  ro[c] = sv / fmaxf(cn, 1.f);
  ro[HID + c] = sv;
  ro[2*HID + c] = unkey(mx[g*HID + c]);
  __syncthreads();
  float acc = b1[c];
  for (int k = 0; k < 3*HID; ++k) acc += ro[k] * W1[k*HID + c];
  r1[c] = fmaxf(acc, 0.f);
  __syncthreads();
  if (c < TGT) {
    float o = b2[c];
    for (int k = 0; k < HID; ++k) o += r1[k] * W2[k*TGT + c];
    out[g*TGT + c] = o;
  }
}

extern "C" void kernel_launch(void* const* d_in, const int* in_sizes, int n_in,
                              void* d_out, int out_size, void* d_ws, size_t ws_size,
                              hipStream_t stream) {
  const int*   eidx = (const int*)d_in[1];
  const int*   srci = eidx;
  const int*   dsti = eidx + N_EDGES;
  const float* ea   = (const float*)d_in[2];
  const int*   batch= (const int*)d_in[3];
  const float* nemb = (const float*)d_in[4];
  const float* eW   = (const float*)d_in[5];
  const float* eb   = (const float*)d_in[6];
  const float* mW1  = (const float*)d_in[7];
  const float* mb1  = (const float*)d_in[8];
  const float* mW2  = (const float*)d_in[9];
  const float* mb2  = (const float*)d_in[10];
  const float* sW   = (const float*)d_in[11];
  const float* sb   = (const float*)d_in[12];
  const float* uW1  = (const float*)d_in[13];
  const float* ub1  = (const float*)d_in[14];
  const float* uW2  = (const float*)d_in[15];
  const float* ub2  = (const float*)d_in[16];
  const float* nW1  = (const float*)d_in[17];
  const float* nb1  = (const float*)d_in[18];
  const float* nW2  = (const float*)d_in[19];
  const float* nb2  = (const float*)d_in[20];
  const float* oW1  = (const float*)d_in[21];
  const float* ob1  = (const float*)d_in[22];
  const float* oW2  = (const float*)d_in[23];
  const float* ob2  = (const float*)d_in[24];

  // workspace layout (total 111,237,760 B)
  char* ws = (char*)d_ws;
  float* sbuf = (float*)(ws + 0);                      //    32,768 B
  float* cnt  = (float*)(ws + 32768);                  //       256 B
  unsigned* mx= (unsigned*)(ws + 33024);               //    32,768 B
  short* pMsg = (short*)(ws + 65792);                  //   524,288 B (4 layers x [W1|W2])
  short* puW1 = (short*)(ws + 590080);                 //   131,072 B
  short* puW2 = (short*)(ws + 721152);                 //   131,072 B
  short* pnW1 = (short*)(ws + 852224);                 //    32,768 B
  short* pnW2 = (short*)(ws + 884992);                 //    32,768 B
  int* hist   = (int*)(ws + 917760);                   //    80,000 B
  int* cursor = (int*)(ws + 997760);                   //    80,000 B
  int* offs   = (int*)(ws + 1077760);                  //    80,000 B
  unsigned short* ssrc = (unsigned short*)(ws + 1157760); // 640,000 B
  unsigned short* sdst = (unsigned short*)(ws + 1797760); // 640,000 B
  float* sea  = (float*)(ws + 2437760);                // 1,280,000 B
  unsigned short* e = (unsigned short*)(ws + 3717760); // 81,920,000 B
  float* h    = (float*)(ws + 85637760);               // 10,240,000 B
  float* agg  = (float*)(ws + 95877760);               // 10,240,000 B (h2 aliases agg)
  unsigned short* hb = (unsigned short*)(ws + 106117760); // 5,120,000 B
  float* h2   = agg;

  // one-time per launch: sort edges by dst
  sort_init<<<(N_NODES + 255) / 256, 256, 0, stream>>>(hist, cursor);
  hist_kernel<<<N_EDGES / 256, 256, 0, stream>>>(dsti, hist);
  scan_kernel<<<1, 1024, 0, stream>>>(hist, offs);
  scatter_kernel<<<N_EDGES / 256, 256, 0, stream>>>(srci, dsti, ea, offs, cursor,
                                                    ssrc, sdst, sea);

  pack_weights<<<1664, 256, 0, stream>>>(mW1, mW2, uW1, uW2, nW1, nW2,
                                         pMsg, puW1, puW2, pnW1, pnW2);
  edge_init<<<N_EDGES / 2, 256, 0, stream>>>(sea, eW, eb, e);
  init_h<<<(N_NODES * HID) / 256, 256, 0, stream>>>(h, nemb, agg, hb);
  init_read<<<33, 256, 0, stream>>>(sbuf, cnt, mx);

  for (int l = 0; l < DEPTHL; ++l) {
    msg_kernel<<<N_EDGES / 128, 512, 0, stream>>>(hb, e, ssrc, sdst,
        pMsg + l*65536, mb1 + l*HID, mb2 + l*HID,
        sW + l*HID, sb + l, agg);
    node_kernel<0><<<(N_NODES + 127) / 128, 512, 0, stream>>>(h, agg,
        puW1 + l*16384, ub1 + l*HID, puW2 + l*16384, ub2 + l*HID, nullptr, hb);
  }
  node_kernel<1><<<(N_NODES + 127) / 128, 512, 0, stream>>>(h, nullptr,
      pnW1, nb1, pnW2, nb2, h2, nullptr);
  accum_kernel<<<(N_NODES + 63) / 64, 256, 0, stream>>>(h2, batch, sbuf, cnt, mx);
  final_kernel<<<NG, 128, 0, stream>>>(sbuf, cnt, mx, oW1, ob1, oW2, ob2, (float*)d_out);
}

// Round 18
// 836.478 us; speedup vs baseline: 1.1852x; 1.1852x over previous
//
#include <hip/hip_runtime.h>

#define N_NODES 20000
#define N_EDGES 320000
#define HID 128
#define NG 64
#define TGT 32
#define DEPTHL 4
#define NTILES 20000
#define MSG_WAVES 14
#define MSG_SLOTS (256 * MSG_WAVES)

typedef __attribute__((ext_vector_type(8))) short s16x8;
typedef __attribute__((ext_vector_type(4))) short s16x4;
typedef __attribute__((ext_vector_type(4))) float f32x4;

__device__ __forceinline__ unsigned short f2b(float f) {
  unsigned u = __builtin_bit_cast(unsigned, f);
  u = (u + 0x7FFFu + ((u >> 16) & 1u)) >> 16;
  return (unsigned short)u;
}
__device__ __forceinline__ float b2f(unsigned short s) {
  return __builtin_bit_cast(float, ((unsigned)s) << 16);
}
__device__ __forceinline__ float silu_f(float x) { return x / (1.f + __expf(-x)); }

__device__ __forceinline__ unsigned fkey(float f) {
  unsigned u = __builtin_bit_cast(unsigned, f);
  return (u & 0x80000000u) ? ~u : (u | 0x80000000u);
}
__device__ __forceinline__ float unkey(unsigned k) {
  unsigned u = (k & 0x80000000u) ? (k ^ 0x80000000u) : ~k;
  return __builtin_bit_cast(float, u);
}

__device__ __forceinline__ f32x4 mfma16(s16x8 a, s16x8 b, f32x4 c) {
  return __builtin_amdgcn_mfma_f32_16x16x32_bf16(a, b, c, 0, 0, 0);
}

// wave-internal LDS write->read fence (guide rule 18)
__device__ __forceinline__ void lds_fence() {
  asm volatile("s_waitcnt lgkmcnt(0)" ::: "memory");
  __builtin_amdgcn_sched_barrier(0);
}

__device__ __forceinline__ s16x8 pack8(float4 a, float4 b) {
  s16x8 p;
  p[0]=(short)f2b(a.x); p[1]=(short)f2b(a.y); p[2]=(short)f2b(a.z); p[3]=(short)f2b(a.w);
  p[4]=(short)f2b(b.x); p[5]=(short)f2b(b.y); p[6]=(short)f2b(b.z); p[7]=(short)f2b(b.w);
  return p;
}

// ---------------- weight packing into MFMA fragment layout (bf16) -------------
// msg weights: per-layer contiguous blob [W1 frags (49152) | W2 frags (16384)],
// 16x16x32 fragment layout for all matrices.
__global__ void pack_weights(const float* __restrict__ mW1, const float* __restrict__ mW2,
                             const float* __restrict__ uW1, const float* __restrict__ uW2,
                             const float* __restrict__ nW1, const float* __restrict__ nW2,
                             short* __restrict__ pMsg,
                             short* __restrict__ puW1, short* __restrict__ puW2,
                             short* __restrict__ pnW1, short* __restrict__ pnW2) {
  int i = blockIdx.x * 256 + threadIdx.x;
  const float* src; short* dst; int K, r;
  if (i < 196608)      { int l = i/49152; r = i % 49152; src = mW1 + l*49152; dst = pMsg + l*65536 + r;        K = 384; }
  else if (i < 262144) { int q = i - 196608; int l = q/16384; r = q % 16384; src = mW2 + l*16384; dst = pMsg + l*65536 + 49152 + r; K = 128; }
  else if (i < 327680) { int q = i - 262144; src = uW1 + (q/16384)*16384; dst = puW1 + q; r = q % 16384; K = 128; }
  else if (i < 393216) { int q = i - 327680; src = uW2 + (q/16384)*16384; dst = puW2 + q; r = q % 16384; K = 128; }
  else if (i < 409600) { int q = i - 393216; src = nW1; dst = pnW1 + q; r = q; K = 128; }
  else if (i < 425984) { int q = i - 409600; src = nW2; dst = pnW2 + q; r = q; K = 128; }
  else return;
  int j = r & 7, lane = (r >> 3) & 63, q2 = r >> 9;
  int KT = K >> 5;
  int kt = q2 % KT, ct = q2 / KT;
  int k = kt*32 + ((lane >> 4) << 3) + j;
  int col = ct*16 + (lane & 15);
  dst[0] = (short)f2b(src[k*HID + col]);
}

// ---------------- edge sort by dst: hist -> scan -> scatter -------------------
__global__ void sort_init(int* __restrict__ hist, int* __restrict__ cursor) {
  int i = blockIdx.x * 256 + threadIdx.x;
  if (i < N_NODES) { hist[i] = 0; cursor[i] = 0; }
}

__global__ void hist_kernel(const int* __restrict__ dst, int* __restrict__ hist) {
  int e = blockIdx.x * 256 + threadIdx.x;
  if (e < N_EDGES) atomicAdd(&hist[dst[e]], 1);
}

__global__ __launch_bounds__(1024) void scan_kernel(const int* __restrict__ hist,
                                                    int* __restrict__ offs) {
  __shared__ int part[1024];
  int t = threadIdx.x;
  int base = t * 20;
  int loc[20];
  int s = 0;
#pragma unroll
  for (int i = 0; i < 20; ++i) {
    loc[i] = s;
    int n = base + i;
    s += (n < N_NODES ? hist[n] : 0);
  }
  part[t] = s;
  __syncthreads();
  for (int st = 1; st < 1024; st <<= 1) {
    int v = (t >= st) ? part[t - st] : 0;
    __syncthreads();
    part[t] += v;
    __syncthreads();
  }
  int pre = (t > 0) ? part[t - 1] : 0;
#pragma unroll
  for (int i = 0; i < 20; ++i) {
    int n = base + i;
    if (n < N_NODES) offs[n] = pre + loc[i];
  }
}

__global__ void scatter_kernel(const int* __restrict__ src, const int* __restrict__ dst,
                               const float* __restrict__ ea, const int* __restrict__ offs,
                               int* __restrict__ cursor,
                               unsigned short* __restrict__ ssrc,
                               unsigned short* __restrict__ sdst,
                               float* __restrict__ sea) {
  int e = blockIdx.x * 256 + threadIdx.x;
  if (e >= N_EDGES) return;
  int d = dst[e];
  int pos = offs[d] + atomicAdd(&cursor[d], 1);
  ssrc[pos] = (unsigned short)src[e];
  sdst[pos] = (unsigned short)d;
  sea[pos] = ea[e];
}

// ---------------- edge feature init (sorted order) ----------------------------
__global__ void edge_init(const float* __restrict__ sea, const float* __restrict__ eW,
                          const float* __restrict__ eb, unsigned short* __restrict__ e) {
  __shared__ float feat[2][9];
  int t = threadIdx.x;
  int le = t >> 7, c = t & 127;
  int edge = blockIdx.x * 2 + le;
  if (c < 9) {
    float d = sea[edge];
    float sc = (float)(1 << (c & 3));
    float v;
    if (c < 4) v = sinf(d / sc);
    else if (c < 8) v = cosf(d / sc);
    else v = d;
    feat[le][c] = v;
  }
  __syncthreads();
  float acc = eb[c];
#pragma unroll
  for (int j = 0; j < 9; ++j) acc += feat[le][j] * eW[j*HID + c];
  acc = silu_f(silu_f(acc));
  e[edge*HID + c] = f2b(acc);
}

// h init (f32 + bf16 mirror) AND agg zero-init
__global__ void init_h(float* __restrict__ h, const float* __restrict__ ne,
                       float* __restrict__ agg, unsigned short* __restrict__ hb) {
  int i = blockIdx.x * 256 + threadIdx.x;
  if (i < N_NODES * HID) {
    float v = ne[i & 127];
    h[i] = v; hb[i] = f2b(v); agg[i] = 0.f;
  }
}

__global__ void init_read(float* __restrict__ s, float* __restrict__ cnt, unsigned* __restrict__ mx) {
  int i = blockIdx.x * 256 + threadIdx.x;
  if (i < NG * HID) { s[i] = 0.f; mx[i] = 0x007FFFFFu; } // key(-inf)
  if (i < NG) cnt[i] = 0.f;
}

// ---------------- fused per-layer edge kernel ---------------------------------
// 256 persistent blocks (1/CU) x 14 independent waves; layer weights staged to
// LDS once per block (131072 B) + 2KB wave-private t1f = 159744 B. Each wave
// loops ~6 strided 16-edge tiles. t1 transpose is TWO-PHASE (ct 0-3 then 4-7)
// so it fits the 2KB slice (round-9-proven; round-17's one-phase overflowed).
__global__ __launch_bounds__(896) void msg_kernel(
    const unsigned short* __restrict__ hb, unsigned short* __restrict__ e,
    const unsigned short* __restrict__ ssrc, const unsigned short* __restrict__ sdst,
    const short* __restrict__ Wp, const float* __restrict__ b1,
    const float* __restrict__ b2,
    const float* __restrict__ sW, const float* __restrict__ sbp,
    float* __restrict__ agg) {
  __shared__ __align__(16) short smem[79872];   // 159744 B
  short* sW1 = smem;                 // 49152 shorts
  short* sW2 = smem + 49152;         // 16384 shorts
  int t = threadIdx.x;
  int wv = t >> 6, lane = t & 63;
  int l15 = lane & 15, hi = lane >> 4;
  short* myt1 = smem + 65536 + wv * 1024;   // 2048 B per wave

  // ---- stage layer weights into LDS (one linear copy; sole block barrier) ----
  {
    const s16x8* Wg = (const s16x8*)Wp;
    s16x8* Wl = (s16x8*)smem;
    for (int i = t; i < 8192; i += 896) Wl[i] = Wg[i];
  }
  __syncthreads();

  float sb_v = sbp[0];
  int slot = blockIdx.x * MSG_WAVES + wv;

#pragma unroll 1
  for (int it = 0; it < 6; ++it) {
    int tile = slot + MSG_SLOTS * it;
    if (tile >= NTILES) break;
    int edge = tile * 16 + l15;
    int si = ssrc[edge];
    int d  = sdst[edge];

    // ---- B-fragments: all 12 issued up-front ----
    s16x8 bfrag[12];
#pragma unroll
    for (int kt = 0; kt < 4; ++kt)
      bfrag[kt] = *(const s16x8*)(hb + si*HID + kt*32 + hi*8);
#pragma unroll
    for (int kt = 0; kt < 4; ++kt)
      bfrag[4+kt] = *(const s16x8*)(hb + d*HID + kt*32 + hi*8);
#pragma unroll
    for (int kt = 0; kt < 4; ++kt)
      bfrag[8+kt] = *(const s16x8*)(e + (size_t)edge*HID + kt*32 + hi*8);

    // ---- GEMM1: t1^T = W1^T @ m_in^T (K=384), weights from LDS ----
    f32x4 acc1[8];
#pragma unroll
    for (int ct = 0; ct < 8; ++ct) acc1[ct] = f32x4{0.f, 0.f, 0.f, 0.f};
#pragma unroll
    for (int kt = 0; kt < 12; ++kt) {
#pragma unroll
      for (int ct = 0; ct < 8; ++ct) {
        s16x8 afr = *(const s16x8*)&sW1[((ct*12 + kt)*64 + lane)*8];
        acc1[ct] = mfma16(afr, bfrag[kt], acc1[ct]);
      }
    }

    // ---- eold prefetch (latency hides under transpose/GEMM2) ----
    uint2 eold[8];
#pragma unroll
    for (int ct = 0; ct < 8; ++ct)
      eold[ct] = *(const uint2*)(e + (size_t)edge*HID + ct*16 + hi*4);

    // ---- two-phase silu+transpose (2KB slice) + GEMM2, weights from LDS ----
    f32x4 acc2[8];
#pragma unroll
    for (int ct = 0; ct < 8; ++ct) acc2[ct] = f32x4{0.f, 0.f, 0.f, 0.f};
#pragma unroll
    for (int p = 0; p < 2; ++p) {
#pragma unroll
      for (int c4 = 0; c4 < 4; ++c4) {
        int ct = 4*p + c4;
        f32x4 bias = *(const f32x4*)(b1 + ct*16 + hi*4);
        s16x4 pk4;
#pragma unroll
        for (int r = 0; r < 4; ++r) pk4[r] = (short)f2b(silu_f(acc1[ct][r] + bias[r]));
        *(s16x4*)&myt1[((2*c4 + (hi >> 1))*16 + l15)*8 + (hi & 1)*4] = pk4;
      }
      lds_fence();   // write -> read
#pragma unroll
      for (int k2 = 0; k2 < 2; ++k2) {
        int kt = 2*p + k2;
        s16x8 bfr = *(const s16x8*)&myt1[((k2*4 + hi)*16 + l15)*8];
#pragma unroll
        for (int ct = 0; ct < 8; ++ct) {
          s16x8 afr = *(const s16x8*)&sW2[((ct*4 + kt)*64 + lane)*8];
          acc2[ct] = mfma16(afr, bfr, acc2[ct]);
        }
      }
      lds_fence();   // read -> next-phase overwrite
    }

    // ---- pass 1: m = silu(acc2+b2) packed to bf16 (mpk); gate dot ----
    uint2 mpk[8];
    float wpart = 0.f;
#pragma unroll
    for (int ct = 0; ct < 8; ++ct) {
      f32x4 bias = *(const f32x4*)(b2 + ct*16 + hi*4);
      f32x4 swv  = *(const f32x4*)(sW + ct*16 + hi*4);
      f32x4 mv;
#pragma unroll
      for (int r = 0; r < 4; ++r) {
        mv[r] = silu_f(acc2[ct][r] + bias[r]);
        wpart += mv[r] * swv[r];
      }
      mpk[ct].x = (unsigned)f2b(mv[0]) | ((unsigned)f2b(mv[1]) << 16);
      mpk[ct].y = (unsigned)f2b(mv[2]) | ((unsigned)f2b(mv[3]) << 16);
    }
    wpart += __shfl_xor(wpart, 16);
    wpart += __shfl_xor(wpart, 32);
    float wg = 1.f / (1.f + __expf(-(wpart + sb_v)));

    // head lanes + segment masks (dst-sorted 16-edge group)
    int pd = __shfl_up(d, 1, 16);
    bool head = (l15 == 0) || (pd != d);
    int okbits = 0;
#pragma unroll
    for (int i = 0; i < 4; ++i) {
      int off = 1 << i;
      int nd = __shfl_down(d, off, 16);
      if ((l15 + off < 16) && (nd == d)) okbits |= (1 << i);
    }
    float* aggrow = agg + d*HID;

    // ---- pass 2 per ct: unpack m, e RMW, segmented suffix-sum, head atomics --
#pragma unroll
    for (int ct = 0; ct < 8; ++ct) {
      float m0 = b2f((unsigned short)(mpk[ct].x & 0xFFFFu));
      float m1 = b2f((unsigned short)(mpk[ct].x >> 16));
      float m2 = b2f((unsigned short)(mpk[ct].y & 0xFFFFu));
      float m3 = b2f((unsigned short)(mpk[ct].y >> 16));

      uint2 cur = eold[ct];
      float f0 = b2f((unsigned short)(cur.x & 0xFFFFu)) + m0;
      float f1 = b2f((unsigned short)(cur.x >> 16))     + m1;
      float f2v = b2f((unsigned short)(cur.y & 0xFFFFu)) + m2;
      float f3 = b2f((unsigned short)(cur.y >> 16))     + m3;
      uint2 nw;
      nw.x = (unsigned)f2b(f0)  | ((unsigned)f2b(f1) << 16);
      nw.y = (unsigned)f2b(f2v) | ((unsigned)f2b(f3) << 16);
      *(uint2*)(e + (size_t)edge*HID + ct*16 + hi*4) = nw;

      f32x4 v;
      v[0] = m0 * wg; v[1] = m1 * wg; v[2] = m2 * wg; v[3] = m3 * wg;
#pragma unroll
      for (int i = 0; i < 4; ++i) {
        int off = 1 << i;
        bool ok = (okbits >> i) & 1;
#pragma unroll
        for (int r = 0; r < 4; ++r) {
          float nv = __shfl_down(v[r], off, 16);
          if (ok) v[r] += nv;
        }
      }
      if (head) {
        float* ap = aggrow + ct*16 + hi*4;
        atomicAdd(ap + 0, v[0]);
        atomicAdd(ap + 1, v[1]);
        atomicAdd(ap + 2, v[2]);
        atomicAdd(ap + 3, v[3]);
      }
    }
  }
}

// ---------------- node MLP kernel (8 independent waves/block, 16 nodes/wave) --
// MODE 0: h += MLP(agg+h), hb = bf16(h), agg = 0.  MODE 1: out = MLP(h).
template<int MODE>
__global__ __launch_bounds__(512) void node_kernel(
    float* __restrict__ h, float* __restrict__ agg,
    const short* __restrict__ W1p, const float* __restrict__ b1,
    const short* __restrict__ W2p, const float* __restrict__ b2,
    float* __restrict__ out, unsigned short* __restrict__ hb) {
  __shared__ __align__(16) short t1f[8][2048];
  int t = threadIdx.x;
  int wv = t >> 6, lane = t & 63;
  int l15 = lane & 15, hi = lane >> 4;
  int node = blockIdx.x * 128 + wv * 16 + l15;
  bool valid = node < N_NODES;
  int nodec = valid ? node : (N_NODES - 1);

  s16x8 bfrag[4];
#pragma unroll
  for (int kt = 0; kt < 4; ++kt) {
    const float* hp = h + nodec*HID + kt*32 + hi*8;
    float4 v0 = *(const float4*)hp;
    float4 v1 = *(const float4*)(hp + 4);
    if (MODE == 0) {
      float* ap = agg + nodec*HID + kt*32 + hi*8;
      float4 a0 = *(const float4*)ap;
      float4 a1 = *(const float4*)(ap + 4);
      v0.x += a0.x; v0.y += a0.y; v0.z += a0.z; v0.w += a0.w;
      v1.x += a1.x; v1.y += a1.y; v1.z += a1.z; v1.w += a1.w;
      if (valid) {
        float4 z = {0.f, 0.f, 0.f, 0.f};
        *(float4*)ap = z;
        *(float4*)(ap + 4) = z;
      }
    }
    bfrag[kt] = pack8(v0, v1);
  }

  f32x4 acc1[8];
#pragma unroll
  for (int ct = 0; ct < 8; ++ct) acc1[ct] = f32x4{0.f, 0.f, 0.f, 0.f};
#pragma unroll
  for (int kt = 0; kt < 4; ++kt) {
#pragma unroll
    for (int ct = 0; ct < 8; ++ct) {
      s16x8 afr = *(const s16x8*)(W1p + ((ct*4 + kt)*64 + lane)*8);
      acc1[ct] = mfma16(afr, bfrag[kt], acc1[ct]);
    }
  }
  short* myt1 = &t1f[wv][0];
#pragma unroll
  for (int ct = 0; ct < 8; ++ct) {
    f32x4 bias = *(const f32x4*)(b1 + ct*16 + hi*4);
    s16x4 pk4;
#pragma unroll
    for (int r = 0; r < 4; ++r) pk4[r] = (short)f2b(silu_f(acc1[ct][r] + bias[r]));
    *(s16x4*)&myt1[((2*ct + (hi >> 1))*16 + l15)*8 + (hi & 1)*4] = pk4;
  }
  lds_fence();

  f32x4 acc2[8];
#pragma unroll
  for (int ct = 0; ct < 8; ++ct) acc2[ct] = f32x4{0.f, 0.f, 0.f, 0.f};
#pragma unroll
  for (int kt = 0; kt < 4; ++kt) {
    s16x8 bfr = *(const s16x8*)&myt1[((kt*4 + hi)*16 + l15)*8];
#pragma unroll
    for (int ct = 0; ct < 8; ++ct) {
      s16x8 afr = *(const s16x8*)(W2p + ((ct*4 + kt)*64 + lane)*8);
      acc2[ct] = mfma16(afr, bfr, acc2[ct]);
    }
  }
  if (valid) {
#pragma unroll
    for (int ct = 0; ct < 8; ++ct) {
      f32x4 bias = *(const f32x4*)(b2 + ct*16 + hi*4);
      float* op = (MODE == 0 ? h : out) + node*HID + ct*16 + hi*4;
      float4 res;
      if (MODE == 0) {
        float4 cur = *(const float4*)op;
        res.x = cur.x + acc2[ct][0] + bias[0];
        res.y = cur.y + acc2[ct][1] + bias[1];
        res.z = cur.z + acc2[ct][2] + bias[2];
        res.w = cur.w + acc2[ct][3] + bias[3];
      } else {
        res.x = acc2[ct][0] + bias[0];
        res.y = acc2[ct][1] + bias[1];
        res.z = acc2[ct][2] + bias[2];
        res.w = acc2[ct][3] + bias[3];
      }
      *(float4*)op = res;
      if (MODE == 0) {
        uint2 nb;
        nb.x = (unsigned)f2b(res.x) | ((unsigned)f2b(res.y) << 16);
        nb.y = (unsigned)f2b(res.z) | ((unsigned)f2b(res.w) << 16);
        *(uint2*)(hb + node*HID + ct*16 + hi*4) = nb;
      }
    }
  }
}

// ---------------- per-graph reductions (sorted batch, per-thread run-flush) ---
__global__ void accum_kernel(const float* __restrict__ h2, const int* __restrict__ batch,
                             float* __restrict__ s, float* __restrict__ cnt,
                             unsigned* __restrict__ mx) {
  int c = threadIdx.x & 127;
  int lr = threadIdx.x >> 7;
  int base = blockIdx.x * 64;
  int cur = -1; float sum = 0.f, mxv = -3.0e38f, count = 0.f;
  for (int i = 0; i < 32; ++i) {
    int node = base + lr + 2 * i;
    if (node >= N_NODES) break;
    int g = batch[node];
    if (g != cur) {
      if (cur >= 0) {
        atomicAdd(&s[cur*HID + c], sum);
        atomicMax(&mx[cur*HID + c], fkey(mxv));
        if (c == 0) atomicAdd(&cnt[cur], count);
      }
      cur = g; sum = 0.f; mxv = -3.0e38f; count = 0.f;
    }
    float v = h2[node*HID + c];
    sum += v; mxv = fmaxf(mxv, v); count += 1.f;
  }
  if (cur >= 0) {
    atomicAdd(&s[cur*HID + c], sum);
    atomicMax(&mx[cur*HID + c], fkey(mxv));
    if (c == 0) atomicAdd(&cnt[cur], count);
  }
}

// ---------------- readout MLP -------------------------------------------------
__global__ void final_kernel(const float* __restrict__ s, const float* __restrict__ cnt,
                             const unsigned* __restrict__ mx,
                             const float* __restrict__ W1, const float* __restrict__ b1,
                             const float* __restrict__ W2, const float* __restrict__ b2,
                             float* __restrict__ out) {
  __shared__ float ro[3 * HID];
  __shared__ float r1[HID];
  int g = blockIdx.x, c = threadIdx.x;
  float sv = s[g*HID + c];
  float cn = cnt[g];
  ro[c] = sv / fmaxf(cn, 1.f);
  ro[HID + c] = sv;
  ro[2*HID + c] = unkey(mx[g*HID + c]);
  __syncthreads();
  float acc = b1[c];
  for (int k = 0; k < 3*HID; ++k) acc += ro[k] * W1[k*HID + c];
  r1[c] = fmaxf(acc, 0.f);
  __syncthreads();
  if (c < TGT) {
    float o = b2[c];
    for (int k = 0; k < HID; ++k) o += r1[k] * W2[k*TGT + c];
    out[g*TGT + c] = o;
  }
}

extern "C" void kernel_launch(void* const* d_in, const int* in_sizes, int n_in,
                              void* d_out, int out_size, void* d_ws, size_t ws_size,
                              hipStream_t stream) {
  const int*   eidx = (const int*)d_in[1];
  const int*   srci = eidx;
  const int*   dsti = eidx + N_EDGES;
  const float* ea   = (const float*)d_in[2];
  const int*   batch= (const int*)d_in[3];
  const float* nemb = (const float*)d_in[4];
  const float* eW   = (const float*)d_in[5];
  const float* eb   = (const float*)d_in[6];
  const float* mW1  = (const float*)d_in[7];
  const float* mb1  = (const float*)d_in[8];
  const float* mW2  = (const float*)d_in[9];
  const float* mb2  = (const float*)d_in[10];
  const float* sW   = (const float*)d_in[11];
  const float* sb   = (const float*)d_in[12];
  const float* uW1  = (const float*)d_in[13];
  const float* ub1  = (const float*)d_in[14];
  const float* uW2  = (const float*)d_in[15];
  const float* ub2  = (const float*)d_in[16];
  const float* nW1  = (const float*)d_in[17];
  const float* nb1  = (const float*)d_in[18];
  const float* nW2  = (const float*)d_in[19];
  const float* nb2  = (const float*)d_in[20];
  const float* oW1  = (const float*)d_in[21];
  const float* ob1  = (const float*)d_in[22];
  const float* oW2  = (const float*)d_in[23];
  const float* ob2  = (const float*)d_in[24];

  // workspace layout (total 111,237,760 B)
  char* ws = (char*)d_ws;
  float* sbuf = (float*)(ws + 0);                      //    32,768 B
  float* cnt  = (float*)(ws + 32768);                  //       256 B
  unsigned* mx= (unsigned*)(ws + 33024);               //    32,768 B
  short* pMsg = (short*)(ws + 65792);                  //   524,288 B (4 layers x [W1|W2])
  short* puW1 = (short*)(ws + 590080);                 //   131,072 B
  short* puW2 = (short*)(ws + 721152);                 //   131,072 B
  short* pnW1 = (short*)(ws + 852224);                 //    32,768 B
  short* pnW2 = (short*)(ws + 884992);                 //    32,768 B
  int* hist   = (int*)(ws + 917760);                   //    80,000 B
  int* cursor = (int*)(ws + 997760);                   //    80,000 B
  int* offs   = (int*)(ws + 1077760);                  //    80,000 B
  unsigned short* ssrc = (unsigned short*)(ws + 1157760); // 640,000 B
  unsigned short* sdst = (unsigned short*)(ws + 1797760); // 640,000 B
  float* sea  = (float*)(ws + 2437760);                // 1,280,000 B
  unsigned short* e = (unsigned short*)(ws + 3717760); // 81,920,000 B
  float* h    = (float*)(ws + 85637760);               // 10,240,000 B
  float* agg  = (float*)(ws + 95877760);               // 10,240,000 B (h2 aliases agg)
  unsigned short* hb = (unsigned short*)(ws + 106117760); // 5,120,000 B
  float* h2   = agg;

  // one-time per launch: sort edges by dst
  sort_init<<<(N_NODES + 255) / 256, 256, 0, stream>>>(hist, cursor);
  hist_kernel<<<N_EDGES / 256, 256, 0, stream>>>(dsti, hist);
  scan_kernel<<<1, 1024, 0, stream>>>(hist, offs);
  scatter_kernel<<<N_EDGES / 256, 256, 0, stream>>>(srci, dsti, ea, offs, cursor,
                                                    ssrc, sdst, sea);

  pack_weights<<<1664, 256, 0, stream>>>(mW1, mW2, uW1, uW2, nW1, nW2,
                                         pMsg, puW1, puW2, pnW1, pnW2);
  edge_init<<<N_EDGES / 2, 256, 0, stream>>>(sea, eW, eb, e);
  init_h<<<(N_NODES * HID) / 256, 256, 0, stream>>>(h, nemb, agg, hb);
  init_read<<<33, 256, 0, stream>>>(sbuf, cnt, mx);

  for (int l = 0; l < DEPTHL; ++l) {
    msg_kernel<<<256, 896, 0, stream>>>(hb, e, ssrc, sdst,
        pMsg + l*65536, mb1 + l*HID, mb2 + l*HID,
        sW + l*HID, sb + l, agg);
    node_kernel<0><<<(N_NODES + 127) / 128, 512, 0, stream>>>(h, agg,
        puW1 + l*16384, ub1 + l*HID, puW2 + l*16384, ub2 + l*HID, nullptr, hb);
  }
  node_kernel<1><<<(N_NODES + 127) / 128, 512, 0, stream>>>(h, nullptr,
      pnW1, nb1, pnW2, nb2, h2, nullptr);
  accum_kernel<<<(N_NODES + 63) / 64, 256, 0, stream>>>(h2, batch, sbuf, cnt, mx);
  final_kernel<<<NG, 128, 0, stream>>>(sbuf, cnt, mx, oW1, ob1, oW2, ob2, (float*)d_out);
}

// Round 19
// 787.039 us; speedup vs baseline: 1.2597x; 1.0628x over previous
//
#include <hip/hip_runtime.h>

#define N_NODES 20000
#define N_EDGES 320000
#define HID 128
#define NG 64
#define TGT 32
#define DEPTHL 4
#define NTILES 20000
#define MSG_WAVES 15
#define MSG_SLOTS (256 * MSG_WAVES)

typedef __attribute__((ext_vector_type(8))) short s16x8;
typedef __attribute__((ext_vector_type(4))) short s16x4;
typedef __attribute__((ext_vector_type(4))) float f32x4;

__device__ __forceinline__ unsigned short f2b(float f) {
  unsigned u = __builtin_bit_cast(unsigned, f);
  u = (u + 0x7FFFu + ((u >> 16) & 1u)) >> 16;
  return (unsigned short)u;
}
__device__ __forceinline__ float b2f(unsigned short s) {
  return __builtin_bit_cast(float, ((unsigned)s) << 16);
}
// fast silu/sigmoid: single-instruction v_rcp_f32 (≈1e-5 rel err, fine at bf16)
__device__ __forceinline__ float silu_f(float x) {
  return x * __builtin_amdgcn_rcpf(1.f + __expf(-x));
}
__device__ __forceinline__ float sigmoid_f(float x) {
  return __builtin_amdgcn_rcpf(1.f + __expf(-x));
}

__device__ __forceinline__ unsigned fkey(float f) {
  unsigned u = __builtin_bit_cast(unsigned, f);
  return (u & 0x80000000u) ? ~u : (u | 0x80000000u);
}
__device__ __forceinline__ float unkey(unsigned k) {
  unsigned u = (k & 0x80000000u) ? (k ^ 0x80000000u) : ~k;
  return __builtin_bit_cast(float, u);
}

__device__ __forceinline__ f32x4 mfma16(s16x8 a, s16x8 b, f32x4 c) {
  return __builtin_amdgcn_mfma_f32_16x16x32_bf16(a, b, c, 0, 0, 0);
}

// wave-internal LDS write->read fence (guide rule 18)
__device__ __forceinline__ void lds_fence() {
  asm volatile("s_waitcnt lgkmcnt(0)" ::: "memory");
  __builtin_amdgcn_sched_barrier(0);
}

__device__ __forceinline__ s16x8 pack8(float4 a, float4 b) {
  s16x8 p;
  p[0]=(short)f2b(a.x); p[1]=(short)f2b(a.y); p[2]=(short)f2b(a.z); p[3]=(short)f2b(a.w);
  p[4]=(short)f2b(b.x); p[5]=(short)f2b(b.y); p[6]=(short)f2b(b.z); p[7]=(short)f2b(b.w);
  return p;
}

// ---------------- weight packing into MFMA fragment layout (bf16) -------------
// msg weights: per-layer contiguous blob [W1 frags (49152) | W2 frags (16384)],
// 16x16x32 fragment layout for all matrices.
__global__ void pack_weights(const float* __restrict__ mW1, const float* __restrict__ mW2,
                             const float* __restrict__ uW1, const float* __restrict__ uW2,
                             const float* __restrict__ nW1, const float* __restrict__ nW2,
                             short* __restrict__ pMsg,
                             short* __restrict__ puW1, short* __restrict__ puW2,
                             short* __restrict__ pnW1, short* __restrict__ pnW2) {
  int i = blockIdx.x * 256 + threadIdx.x;
  const float* src; short* dst; int K, r;
  if (i < 196608)      { int l = i/49152; r = i % 49152; src = mW1 + l*49152; dst = pMsg + l*65536 + r;        K = 384; }
  else if (i < 262144) { int q = i - 196608; int l = q/16384; r = q % 16384; src = mW2 + l*16384; dst = pMsg + l*65536 + 49152 + r; K = 128; }
  else if (i < 327680) { int q = i - 262144; src = uW1 + (q/16384)*16384; dst = puW1 + q; r = q % 16384; K = 128; }
  else if (i < 393216) { int q = i - 327680; src = uW2 + (q/16384)*16384; dst = puW2 + q; r = q % 16384; K = 128; }
  else if (i < 409600) { int q = i - 393216; src = nW1; dst = pnW1 + q; r = q; K = 128; }
  else if (i < 425984) { int q = i - 409600; src = nW2; dst = pnW2 + q; r = q; K = 128; }
  else return;
  int j = r & 7, lane = (r >> 3) & 63, q2 = r >> 9;
  int KT = K >> 5;
  int kt = q2 % KT, ct = q2 / KT;
  int k = kt*32 + ((lane >> 4) << 3) + j;
  int col = ct*16 + (lane & 15);
  dst[0] = (short)f2b(src[k*HID + col]);
}

// ---------------- edge sort by dst: hist -> scan -> scatter -------------------
__global__ void sort_init(int* __restrict__ hist, int* __restrict__ cursor) {
  int i = blockIdx.x * 256 + threadIdx.x;
  if (i < N_NODES) { hist[i] = 0; cursor[i] = 0; }
}

__global__ void hist_kernel(const int* __restrict__ dst, int* __restrict__ hist) {
  int e = blockIdx.x * 256 + threadIdx.x;
  if (e < N_EDGES) atomicAdd(&hist[dst[e]], 1);
}

__global__ __launch_bounds__(1024) void scan_kernel(const int* __restrict__ hist,
                                                    int* __restrict__ offs) {
  __shared__ int part[1024];
  int t = threadIdx.x;
  int base = t * 20;
  int loc[20];
  int s = 0;
#pragma unroll
  for (int i = 0; i < 20; ++i) {
    loc[i] = s;
    int n = base + i;
    s += (n < N_NODES ? hist[n] : 0);
  }
  part[t] = s;
  __syncthreads();
  for (int st = 1; st < 1024; st <<= 1) {
    int v = (t >= st) ? part[t - st] : 0;
    __syncthreads();
    part[t] += v;
    __syncthreads();
  }
  int pre = (t > 0) ? part[t - 1] : 0;
#pragma unroll
  for (int i = 0; i < 20; ++i) {
    int n = base + i;
    if (n < N_NODES) offs[n] = pre + loc[i];
  }
}

__global__ void scatter_kernel(const int* __restrict__ src, const int* __restrict__ dst,
                               const float* __restrict__ ea, const int* __restrict__ offs,
                               int* __restrict__ cursor,
                               unsigned short* __restrict__ ssrc,
                               unsigned short* __restrict__ sdst,
                               float* __restrict__ sea) {
  int e = blockIdx.x * 256 + threadIdx.x;
  if (e >= N_EDGES) return;
  int d = dst[e];
  int pos = offs[d] + atomicAdd(&cursor[d], 1);
  ssrc[pos] = (unsigned short)src[e];
  sdst[pos] = (unsigned short)d;
  sea[pos] = ea[e];
}

// ---------------- edge feature init (sorted order) ----------------------------
__global__ void edge_init(const float* __restrict__ sea, const float* __restrict__ eW,
                          const float* __restrict__ eb, unsigned short* __restrict__ e) {
  __shared__ float feat[2][9];
  int t = threadIdx.x;
  int le = t >> 7, c = t & 127;
  int edge = blockIdx.x * 2 + le;
  if (c < 9) {
    float d = sea[edge];
    float sc = (float)(1 << (c & 3));
    float v;
    if (c < 4) v = sinf(d / sc);
    else if (c < 8) v = cosf(d / sc);
    else v = d;
    feat[le][c] = v;
  }
  __syncthreads();
  float acc = eb[c];
#pragma unroll
  for (int j = 0; j < 9; ++j) acc += feat[le][j] * eW[j*HID + c];
  acc = silu_f(silu_f(acc));
  e[edge*HID + c] = f2b(acc);
}

// h init (f32 + bf16 mirror) AND agg zero-init
__global__ void init_h(float* __restrict__ h, const float* __restrict__ ne,
                       float* __restrict__ agg, unsigned short* __restrict__ hb) {
  int i = blockIdx.x * 256 + threadIdx.x;
  if (i < N_NODES * HID) {
    float v = ne[i & 127];
    h[i] = v; hb[i] = f2b(v); agg[i] = 0.f;
  }
}

__global__ void init_read(float* __restrict__ s, float* __restrict__ cnt, unsigned* __restrict__ mx) {
  int i = blockIdx.x * 256 + threadIdx.x;
  if (i < NG * HID) { s[i] = 0.f; mx[i] = 0x007FFFFFu; } // key(-inf)
  if (i < NG) cnt[i] = 0.f;
}

// ---------------- fused per-layer edge kernel ---------------------------------
// 256 persistent blocks (1/CU) x 15 independent waves; layer weights staged to
// LDS once per block (131072 B) + 2KB wave-private t1f = 161792 B. Each wave
// loops ~6 strided 16-edge tiles; two-phase t1 transpose fits the 2KB slice.
__global__ __launch_bounds__(960) void msg_kernel(
    const unsigned short* __restrict__ hb, unsigned short* __restrict__ e,
    const unsigned short* __restrict__ ssrc, const unsigned short* __restrict__ sdst,
    const short* __restrict__ Wp, const float* __restrict__ b1,
    const float* __restrict__ b2,
    const float* __restrict__ sW, const float* __restrict__ sbp,
    float* __restrict__ agg) {
  __shared__ __align__(16) short smem[80896];   // 161792 B
  short* sW1 = smem;                 // 49152 shorts
  short* sW2 = smem + 49152;         // 16384 shorts
  int t = threadIdx.x;
  int wv = t >> 6, lane = t & 63;
  int l15 = lane & 15, hi = lane >> 4;
  short* myt1 = smem + 65536 + wv * 1024;   // 2048 B per wave

  // ---- stage layer weights into LDS (one linear copy; sole block barrier) ----
  {
    const s16x8* Wg = (const s16x8*)Wp;
    s16x8* Wl = (s16x8*)smem;
    for (int i = t; i < 8192; i += 960) Wl[i] = Wg[i];
  }
  __syncthreads();

  float sb_v = sbp[0];
  int slot = blockIdx.x * MSG_WAVES + wv;

#pragma unroll 1
  for (int it = 0; it < 6; ++it) {
    int tile = slot + MSG_SLOTS * it;
    if (tile >= NTILES) break;
    int edge = tile * 16 + l15;
    int si = ssrc[edge];
    int d  = sdst[edge];

    // ---- B-fragments: all 12 issued up-front ----
    s16x8 bfrag[12];
#pragma unroll
    for (int kt = 0; kt < 4; ++kt)
      bfrag[kt] = *(const s16x8*)(hb + si*HID + kt*32 + hi*8);
#pragma unroll
    for (int kt = 0; kt < 4; ++kt)
      bfrag[4+kt] = *(const s16x8*)(hb + d*HID + kt*32 + hi*8);
#pragma unroll
    for (int kt = 0; kt < 4; ++kt)
      bfrag[8+kt] = *(const s16x8*)(e + (size_t)edge*HID + kt*32 + hi*8);

    // ---- GEMM1: t1^T = W1^T @ m_in^T (K=384), weights from LDS ----
    f32x4 acc1[8];
#pragma unroll
    for (int ct = 0; ct < 8; ++ct) acc1[ct] = f32x4{0.f, 0.f, 0.f, 0.f};
#pragma unroll
    for (int kt = 0; kt < 12; ++kt) {
#pragma unroll
      for (int ct = 0; ct < 8; ++ct) {
        s16x8 afr = *(const s16x8*)&sW1[((ct*12 + kt)*64 + lane)*8];
        acc1[ct] = mfma16(afr, bfrag[kt], acc1[ct]);
      }
    }

    // ---- eold prefetch (latency hides under transpose/GEMM2) ----
    uint2 eold[8];
#pragma unroll
    for (int ct = 0; ct < 8; ++ct)
      eold[ct] = *(const uint2*)(e + (size_t)edge*HID + ct*16 + hi*4);

    // ---- two-phase silu+transpose (2KB slice) + GEMM2, weights from LDS ----
    f32x4 acc2[8];
#pragma unroll
    for (int ct = 0; ct < 8; ++ct) acc2[ct] = f32x4{0.f, 0.f, 0.f, 0.f};
#pragma unroll
    for (int p = 0; p < 2; ++p) {
#pragma unroll
      for (int c4 = 0; c4 < 4; ++c4) {
        int ct = 4*p + c4;
        f32x4 bias = *(const f32x4*)(b1 + ct*16 + hi*4);
        s16x4 pk4;
#pragma unroll
        for (int r = 0; r < 4; ++r) pk4[r] = (short)f2b(silu_f(acc1[ct][r] + bias[r]));
        *(s16x4*)&myt1[((2*c4 + (hi >> 1))*16 + l15)*8 + (hi & 1)*4] = pk4;
      }
      lds_fence();   // write -> read
#pragma unroll
      for (int k2 = 0; k2 < 2; ++k2) {
        int kt = 2*p + k2;
        s16x8 bfr = *(const s16x8*)&myt1[((k2*4 + hi)*16 + l15)*8];
#pragma unroll
        for (int ct = 0; ct < 8; ++ct) {
          s16x8 afr = *(const s16x8*)&sW2[((ct*4 + kt)*64 + lane)*8];
          acc2[ct] = mfma16(afr, bfr, acc2[ct]);
        }
      }
      lds_fence();   // read -> next-phase overwrite
    }

    // ---- pass 1: m = silu(acc2+b2) packed to bf16 (mpk); gate dot ----
    uint2 mpk[8];
    float wpart = 0.f;
#pragma unroll
    for (int ct = 0; ct < 8; ++ct) {
      f32x4 bias = *(const f32x4*)(b2 + ct*16 + hi*4);
      f32x4 swv  = *(const f32x4*)(sW + ct*16 + hi*4);
      f32x4 mv;
#pragma unroll
      for (int r = 0; r < 4; ++r) {
        mv[r] = silu_f(acc2[ct][r] + bias[r]);
        wpart += mv[r] * swv[r];
      }
      mpk[ct].x = (unsigned)f2b(mv[0]) | ((unsigned)f2b(mv[1]) << 16);
      mpk[ct].y = (unsigned)f2b(mv[2]) | ((unsigned)f2b(mv[3]) << 16);
    }
    wpart += __shfl_xor(wpart, 16);
    wpart += __shfl_xor(wpart, 32);
    float wg = sigmoid_f(wpart + sb_v);

    // head lanes + segment masks (dst-sorted 16-edge group)
    int pd = __shfl_up(d, 1, 16);
    bool head = (l15 == 0) || (pd != d);
    int okbits = 0;
#pragma unroll
    for (int i = 0; i < 4; ++i) {
      int off = 1 << i;
      int nd = __shfl_down(d, off, 16);
      if ((l15 + off < 16) && (nd == d)) okbits |= (1 << i);
    }
    float* aggrow = agg + d*HID;

    // ---- pass 2 per ct: unpack m, e RMW, segmented suffix-sum, head atomics --
#pragma unroll
    for (int ct = 0; ct < 8; ++ct) {
      float m0 = b2f((unsigned short)(mpk[ct].x & 0xFFFFu));
      float m1 = b2f((unsigned short)(mpk[ct].x >> 16));
      float m2 = b2f((unsigned short)(mpk[ct].y & 0xFFFFu));
      float m3 = b2f((unsigned short)(mpk[ct].y >> 16));

      uint2 cur = eold[ct];
      float f0 = b2f((unsigned short)(cur.x & 0xFFFFu)) + m0;
      float f1 = b2f((unsigned short)(cur.x >> 16))     + m1;
      float f2v = b2f((unsigned short)(cur.y & 0xFFFFu)) + m2;
      float f3 = b2f((unsigned short)(cur.y >> 16))     + m3;
      uint2 nw;
      nw.x = (unsigned)f2b(f0)  | ((unsigned)f2b(f1) << 16);
      nw.y = (unsigned)f2b(f2v) | ((unsigned)f2b(f3) << 16);
      *(uint2*)(e + (size_t)edge*HID + ct*16 + hi*4) = nw;

      f32x4 v;
      v[0] = m0 * wg; v[1] = m1 * wg; v[2] = m2 * wg; v[3] = m3 * wg;
#pragma unroll
      for (int i = 0; i < 4; ++i) {
        int off = 1 << i;
        bool ok = (okbits >> i) & 1;
#pragma unroll
        for (int r = 0; r < 4; ++r) {
          float nv = __shfl_down(v[r], off, 16);
          if (ok) v[r] += nv;
        }
      }
      if (head) {
        float* ap = aggrow + ct*16 + hi*4;
        atomicAdd(ap + 0, v[0]);
        atomicAdd(ap + 1, v[1]);
        atomicAdd(ap + 2, v[2]);
        atomicAdd(ap + 3, v[3]);
      }
    }
  }
}

// ---------------- node MLP kernel (8 independent waves/block, 16 nodes/wave) --
// MODE 0: h += MLP(agg+h), hb = bf16(h), agg = 0.  MODE 1: out = MLP(h).
template<int MODE>
__global__ __launch_bounds__(512) void node_kernel(
    float* __restrict__ h, float* __restrict__ agg,
    const short* __restrict__ W1p, const float* __restrict__ b1,
    const short* __restrict__ W2p, const float* __restrict__ b2,
    float* __restrict__ out, unsigned short* __restrict__ hb) {
  __shared__ __align__(16) short t1f[8][2048];
  int t = threadIdx.x;
  int wv = t >> 6, lane = t & 63;
  int l15 = lane & 15, hi = lane >> 4;
  int node = blockIdx.x * 128 + wv * 16 + l15;
  bool valid = node < N_NODES;
  int nodec = valid ? node : (N_NODES - 1);

  s16x8 bfrag[4];
#pragma unroll
  for (int kt = 0; kt < 4; ++kt) {
    const float* hp = h + nodec*HID + kt*32 + hi*8;
    float4 v0 = *(const float4*)hp;
    float4 v1 = *(const float4*)(hp + 4);
    if (MODE == 0) {
      float* ap = agg + nodec*HID + kt*32 + hi*8;
      float4 a0 = *(const float4*)ap;
      float4 a1 = *(const float4*)(ap + 4);
      v0.x += a0.x; v0.y += a0.y; v0.z += a0.z; v0.w += a0.w;
      v1.x += a1.x; v1.y += a1.y; v1.z += a1.z; v1.w += a1.w;
      if (valid) {
        float4 z = {0.f, 0.f, 0.f, 0.f};
        *(float4*)ap = z;
        *(float4*)(ap + 4) = z;
      }
    }
    bfrag[kt] = pack8(v0, v1);
  }

  f32x4 acc1[8];
#pragma unroll
  for (int ct = 0; ct < 8; ++ct) acc1[ct] = f32x4{0.f, 0.f, 0.f, 0.f};
#pragma unroll
  for (int kt = 0; kt < 4; ++kt) {
#pragma unroll
    for (int ct = 0; ct < 8; ++ct) {
      s16x8 afr = *(const s16x8*)(W1p + ((ct*4 + kt)*64 + lane)*8);
      acc1[ct] = mfma16(afr, bfrag[kt], acc1[ct]);
    }
  }
  short* myt1 = &t1f[wv][0];
#pragma unroll
  for (int ct = 0; ct < 8; ++ct) {
    f32x4 bias = *(const f32x4*)(b1 + ct*16 + hi*4);
    s16x4 pk4;
#pragma unroll
    for (int r = 0; r < 4; ++r) pk4[r] = (short)f2b(silu_f(acc1[ct][r] + bias[r]));
    *(s16x4*)&myt1[((2*ct + (hi >> 1))*16 + l15)*8 + (hi & 1)*4] = pk4;
  }
  lds_fence();

  f32x4 acc2[8];
#pragma unroll
  for (int ct = 0; ct < 8; ++ct) acc2[ct] = f32x4{0.f, 0.f, 0.f, 0.f};
#pragma unroll
  for (int kt = 0; kt < 4; ++kt) {
    s16x8 bfr = *(const s16x8*)&myt1[((kt*4 + hi)*16 + l15)*8];
#pragma unroll
    for (int ct = 0; ct < 8; ++ct) {
      s16x8 afr = *(const s16x8*)(W2p + ((ct*4 + kt)*64 + lane)*8);
      acc2[ct] = mfma16(afr, bfr, acc2[ct]);
    }
  }
  if (valid) {
#pragma unroll
    for (int ct = 0; ct < 8; ++ct) {
      f32x4 bias = *(const f32x4*)(b2 + ct*16 + hi*4);
      float* op = (MODE == 0 ? h : out) + node*HID + ct*16 + hi*4;
      float4 res;
      if (MODE == 0) {
        float4 cur = *(const float4*)op;
        res.x = cur.x + acc2[ct][0] + bias[0];
        res.y = cur.y + acc2[ct][1] + bias[1];
        res.z = cur.z + acc2[ct][2] + bias[2];
        res.w = cur.w + acc2[ct][3] + bias[3];
      } else {
        res.x = acc2[ct][0] + bias[0];
        res.y = acc2[ct][1] + bias[1];
        res.z = acc2[ct][2] + bias[2];
        res.w = acc2[ct][3] + bias[3];
      }
      *(float4*)op = res;
      if (MODE == 0) {
        uint2 nb;
        nb.x = (unsigned)f2b(res.x) | ((unsigned)f2b(res.y) << 16);
        nb.y = (unsigned)f2b(res.z) | ((unsigned)f2b(res.w) << 16);
        *(uint2*)(hb + node*HID + ct*16 + hi*4) = nb;
      }
    }
  }
}

// ---------------- per-graph reductions (sorted batch, per-thread run-flush) ---
__global__ void accum_kernel(const float* __restrict__ h2, const int* __restrict__ batch,
                             float* __restrict__ s, float* __restrict__ cnt,
                             unsigned* __restrict__ mx) {
  int c = threadIdx.x & 127;
  int lr = threadIdx.x >> 7;
  int base = blockIdx.x * 64;
  int cur = -1; float sum = 0.f, mxv = -3.0e38f, count = 0.f;
  for (int i = 0; i < 32; ++i) {
    int node = base + lr + 2 * i;
    if (node >= N_NODES) break;
    int g = batch[node];
    if (g != cur) {
      if (cur >= 0) {
        atomicAdd(&s[cur*HID + c], sum);
        atomicMax(&mx[cur*HID + c], fkey(mxv));
        if (c == 0) atomicAdd(&cnt[cur], count);
      }
      cur = g; sum = 0.f; mxv = -3.0e38f; count = 0.f;
    }
    float v = h2[node*HID + c];
    sum += v; mxv = fmaxf(mxv, v); count += 1.f;
  }
  if (cur >= 0) {
    atomicAdd(&s[cur*HID + c], sum);
    atomicMax(&mx[cur*HID + c], fkey(mxv));
    if (c == 0) atomicAdd(&cnt[cur], count);
  }
}

// ---------------- readout MLP -------------------------------------------------
__global__ void final_kernel(const float* __restrict__ s, const float* __restrict__ cnt,
                             const unsigned* __restrict__ mx,
                             const float* __restrict__ W1, const float* __restrict__ b1,
                             const float* __restrict__ W2, const float* __restrict__ b2,
                             float* __restrict__ out) {
  __shared__ float ro[3 * HID];
  __shared__ float r1[HID];
  int g = blockIdx.x, c = threadIdx.x;
  float sv = s[g*HID + c];
  float cn = cnt[g];
  ro[c] = sv / fmaxf(cn, 1.f);
  ro[HID + c] = sv;
  ro[2*HID + c] = unkey(mx[g*HID + c]);
  __syncthreads();
  float acc = b1[c];
  for (int k = 0; k < 3*HID; ++k) acc += ro[k] * W1[k*HID + c];
  r1[c] = fmaxf(acc, 0.f);
  __syncthreads();
  if (c < TGT) {
    float o = b2[c];
    for (int k = 0; k < HID; ++k) o += r1[k] * W2[k*TGT + c];
    out[g*TGT + c] = o;
  }
}

extern "C" void kernel_launch(void* const* d_in, const int* in_sizes, int n_in,
                              void* d_out, int out_size, void* d_ws, size_t ws_size,
                              hipStream_t stream) {
  const int*   eidx = (const int*)d_in[1];
  const int*   srci = eidx;
  const int*   dsti = eidx + N_EDGES;
  const float* ea   = (const float*)d_in[2];
  const int*   batch= (const int*)d_in[3];
  const float* nemb = (const float*)d_in[4];
  const float* eW   = (const float*)d_in[5];
  const float* eb   = (const float*)d_in[6];
  const float* mW1  = (const float*)d_in[7];
  const float* mb1  = (const float*)d_in[8];
  const float* mW2  = (const float*)d_in[9];
  const float* mb2  = (const float*)d_in[10];
  const float* sW   = (const float*)d_in[11];
  const float* sb   = (const float*)d_in[12];
  const float* uW1  = (const float*)d_in[13];
  const float* ub1  = (const float*)d_in[14];
  const float* uW2  = (const float*)d_in[15];
  const float* ub2  = (const float*)d_in[16];
  const float* nW1  = (const float*)d_in[17];
  const float* nb1  = (const float*)d_in[18];
  const float* nW2  = (const float*)d_in[19];
  const float* nb2  = (const float*)d_in[20];
  const float* oW1  = (const float*)d_in[21];
  const float* ob1  = (const float*)d_in[22];
  const float* oW2  = (const float*)d_in[23];
  const float* ob2  = (const float*)d_in[24];

  // workspace layout (total 111,237,760 B)
  char* ws = (char*)d_ws;
  float* sbuf = (float*)(ws + 0);                      //    32,768 B
  float* cnt  = (float*)(ws + 32768);                  //       256 B
  unsigned* mx= (unsigned*)(ws + 33024);               //    32,768 B
  short* pMsg = (short*)(ws + 65792);                  //   524,288 B (4 layers x [W1|W2])
  short* puW1 = (short*)(ws + 590080);                 //   131,072 B
  short* puW2 = (short*)(ws + 721152);                 //   131,072 B
  short* pnW1 = (short*)(ws + 852224);                 //    32,768 B
  short* pnW2 = (short*)(ws + 884992);                 //    32,768 B
  int* hist   = (int*)(ws + 917760);                   //    80,000 B
  int* cursor = (int*)(ws + 997760);                   //    80,000 B
  int* offs   = (int*)(ws + 1077760);                  //    80,000 B
  unsigned short* ssrc = (unsigned short*)(ws + 1157760); // 640,000 B
  unsigned short* sdst = (unsigned short*)(ws + 1797760); // 640,000 B
  float* sea  = (float*)(ws + 2437760);                // 1,280,000 B
  unsigned short* e = (unsigned short*)(ws + 3717760); // 81,920,000 B
  float* h    = (float*)(ws + 85637760);               // 10,240,000 B
  float* agg  = (float*)(ws + 95877760);               // 10,240,000 B (h2 aliases agg)
  unsigned short* hb = (unsigned short*)(ws + 106117760); // 5,120,000 B
  float* h2   = agg;

  // one-time per launch: sort edges by dst
  sort_init<<<(N_NODES + 255) / 256, 256, 0, stream>>>(hist, cursor);
  hist_kernel<<<N_EDGES / 256, 256, 0, stream>>>(dsti, hist);
  scan_kernel<<<1, 1024, 0, stream>>>(hist, offs);
  scatter_kernel<<<N_EDGES / 256, 256, 0, stream>>>(srci, dsti, ea, offs, cursor,
                                                    ssrc, sdst, sea);

  pack_weights<<<1664, 256, 0, stream>>>(mW1, mW2, uW1, uW2, nW1, nW2,
                                         pMsg, puW1, puW2, pnW1, pnW2);
  edge_init<<<N_EDGES / 2, 256, 0, stream>>>(sea, eW, eb, e);
  init_h<<<(N_NODES * HID) / 256, 256, 0, stream>>>(h, nemb, agg, hb);
  init_read<<<33, 256, 0, stream>>>(sbuf, cnt, mx);

  for (int l = 0; l < DEPTHL; ++l) {
    msg_kernel<<<256, 960, 0, stream>>>(hb, e, ssrc, sdst,
        pMsg + l*65536, mb1 + l*HID, mb2 + l*HID,
        sW + l*HID, sb + l, agg);
    node_kernel<0><<<(N_NODES + 127) / 128, 512, 0, stream>>>(h, agg,
        puW1 + l*16384, ub1 + l*HID, puW2 + l*16384, ub2 + l*HID, nullptr, hb);
  }
  node_kernel<1><<<(N_NODES + 127) / 128, 512, 0, stream>>>(h, nullptr,
      pnW1, nb1, pnW2, nb2, h2, nullptr);
  accum_kernel<<<(N_NODES + 63) / 64, 256, 0, stream>>>(h2, batch, sbuf, cnt, mx);
  final_kernel<<<NG, 128, 0, stream>>>(sbuf, cnt, mx, oW1, ob1, oW2, ob2, (float*)d_out);
}